// Round 4
// baseline (84.210 us; speedup 1.0000x reference)
//
#include <hip/hip_runtime.h>
#include <math.h>

// Modulated deformable conv v2: B=4, C=256, H=W=64, O=256, K=3, PAD=1
// r22: FUSION. K2 (offset/mask conv, r13 body verbatim) fused into K3
//      (deform conv, r18 body verbatim -- the fastest measured K3) with an
//      LDS handoff: K2 epilogue -> offm_s[27][64] in LDS, barrier, r18
//      table-build reads LDS, r18 main loop. Block mapping (b,row) is 1:1
//      between producer and consumer, so no cross-block traffic. Removes a
//      launch + offm HBM round trip + global epilogue/table phases.
//      K1 nhwcpack verbatim.

constexpr int Bn = 4;
constexpr int Cn = 256;
constexpr int Hn = 64;
constexpr int Wn = 64;
constexpr int On = 256;
constexpr int PB = Hn * Wn;     // 4096
constexpr int NCH = 27;

typedef __attribute__((ext_vector_type(8))) short bf16x8;  // 8 bf16 (4 VGPRs)
typedef __attribute__((ext_vector_type(4))) float f32x4;

union FragU { uint4 u; bf16x8 h; };

__device__ inline ushort f2bf(float f) {
    uint u = __builtin_bit_cast(uint, f);
    return (ushort)((u + 0x7fffu + ((u >> 16) & 1u)) >> 16);
}
__device__ inline float bf2f(ushort h) {
    uint u = (uint)h << 16;
    return __builtin_bit_cast(float, u);
}
__device__ inline float bflo(uint u) { u <<= 16;          return __builtin_bit_cast(float, u); }
__device__ inline float bfhi(uint u) { u &= 0xffff0000u;  return __builtin_bit_cast(float, u); }

// ---------------------------------------------------------------- kernel 1
// (r16/r17-proven) NCHW fp32 -> NHWC bf16 hi/lo planes + weight packing.
__global__ __launch_bounds__(256)
void nhwcpack_kernel(const float* __restrict__ x,
                     const float* __restrict__ w,
                     const float* __restrict__ offw,
                     const float* __restrict__ modw,
                     ushort* __restrict__ xbf, ushort* __restrict__ xlr,
                     ushort* __restrict__ wTb,
                     ushort* __restrict__ owh, ushort* __restrict__ owl)
{
    const int bid = blockIdx.x;
    const int b = bid >> 7, seg = bid & 127;
    const int t = threadIdx.x;
    __shared__ float tile[32][257];

    const float* src = x + (size_t)b * Cn * PB + seg * 32;
    #pragma unroll 4
    for (int i = 0; i < 32; ++i) {
        const int idx = i * 256 + t;
        const int c = idx >> 5, p = idx & 31;
        tile[p][c] = src[(size_t)c * PB + p];
    }
    __syncthreads();

    const int pr = t & 127;
    const int r0 = (t >> 7) * 16;
    uint* dH = reinterpret_cast<uint*>(xbf + ((size_t)b * PB + seg * 32) * 256);
    uint* dL = reinterpret_cast<uint*>(xlr + ((size_t)b * PB + seg * 32) * 256);
    #pragma unroll 4
    for (int i = 0; i < 16; ++i) {
        const int row = r0 + i;
        const float v0 = tile[row][2 * pr];
        const float v1 = tile[row][2 * pr + 1];
        const ushort h0 = f2bf(v0), h1 = f2bf(v1);
        const ushort l0 = f2bf(v0 - bf2f(h0));
        const ushort l1 = f2bf(v1 - bf2f(h1));
        dH[(size_t)row * 128 + pr] = (uint)h0 | ((uint)h1 << 16);
        dL[(size_t)row * 128 + pr] = (uint)l0 | ((uint)l1 << 16);
    }

    #pragma unroll 1
    for (int u = 0; u < 5; ++u) {
        int unit = (u < 4) ? bid * 4 + u : (bid < 256 ? 2048 + bid : -1);
        if (unit < 0) break;
        const int tap = unit >> 8, c = unit & 255;
        const int o = t;
        wTb[((size_t)(unit >> 3) * 256 + o) * 8 + (c & 7)] =
            f2bf(w[((size_t)o * Cn + c) * 9 + tap]);
        if (o < 32) {
            float v = 0.f;
            if (o < 18)      v = offw[((size_t)o * Cn + c) * 9 + tap];
            else if (o < 27) v = modw[((size_t)(o - 18) * Cn + c) * 9 + tap];
            const ushort h = f2bf(v);
            const ushort l = f2bf(v - bf2f(h));
            const size_t base = ((size_t)(unit >> 3) * 32 + o) * 8 + (c & 7);
            owh[base] = h;
            owl[base] = l;
        }
    }
}

// ---------------------------------------------------------------- kernel 2
// FUSED offset/mask conv + deformable conv. grid 256 = (b,row) XCD-swizzled,
// 512 threads = 8 waves.
// Phase A = r13 offmask body (verbatim), epilogue -> offm_s in LDS.
// Phase B = r18 deform body (verbatim), table build reads offm_s.
// LDS: 64KB overlay region (colsH/colsL | s_off/s_wgt/cols) + 6.9KB offm_s.
__global__ __launch_bounds__(512, 2)
void offdeform_kernel(const ushort* __restrict__ xbf,
                      const ushort* __restrict__ xlr,
                      const float* __restrict__ offb,
                      const float* __restrict__ modb,
                      const ushort* __restrict__ owh,
                      const ushort* __restrict__ owl,
                      const ushort* __restrict__ wTb,
                      float* __restrict__ out)
{
    const int hw = blockIdx.x;
    const int blk = (hw & 7) * 32 + (hw >> 3);   // XCD swizzle (256 = 8*32)
    const int b = blk >> 6, row = blk & 63;
    const int p0 = row * 64;
    const int t = threadIdx.x;
    const int lane = t & 63;
    const int wv  = t >> 6;
    const int l15 = lane & 15;
    const int g   = lane >> 4;
    const int mt  = wv >> 2;
    const int nt4 = wv & 3;

    __shared__ __align__(16) char smraw[65536];
    __shared__ float offm_s[NCH][64];

    // Phase-A views (64 KB)
    uint (*colsH)[1024] = reinterpret_cast<uint (*)[1024]>(smraw);
    uint (*colsL)[1024] = reinterpret_cast<uint (*)[1024]>(smraw + 32768);
    // Phase-B views (34.8 KB, overlaid on the same region)
    int4*   s_off = reinterpret_cast<int4*>(smraw);                    //  9216 B
    float4* s_wgt = reinterpret_cast<float4*>(smraw + 9216);           //  9216 B
    uint (*cols)[1024] = reinterpret_cast<uint (*)[1024]>(smraw + 18432); // 16384 B

    const int posT0 = t >> 4;          // 0..31
    const int chq   = t & 15;
    const int ws0 = posT0 * 16
        + 4 * ((chq >> 2) ^ (posT0 & 3) ^ ((posT0 >> 2) & 3)) + (chq & 3);
    const int posT1 = posT0 + 32;
    const int ws1 = posT1 * 16
        + 4 * ((chq >> 2) ^ (posT1 & 3) ^ ((posT1 >> 2) & 3)) + (chq & 3);

    // ======================= Phase A: offset/mask conv (r13 verbatim) ====
    {
        const ushort* xhb = xbf + (size_t)b * PB * 256;
        const ushort* xlb = xlr + (size_t)b * PB * 256;
        const uint4* owhV = reinterpret_cast<const uint4*>(owh);
        const uint4* owlV = reinterpret_cast<const uint4*>(owl);

        f32x4 acc = (f32x4){0.f, 0.f, 0.f, 0.f};
        const int p = nt4 * 16 + l15;
        const int ridx = p * 4 + (g ^ (p & 3) ^ ((p >> 2) & 3));

        #pragma unroll 1
        for (int tap = 0; tap < 9; ++tap) {
            const int ty = tap / 3, tx = tap % 3;
            const int y = row - 1 + ty;
            const int xc0 = posT0 - 1 + tx;
            const int xc1 = posT1 - 1 + tx;
            const bool ok0 = (y >= 0) && (y < Hn) && (xc0 >= 0) && (xc0 < Wn);
            const bool ok1 = (y >= 0) && (y < Hn) && (xc1 >= 0) && (xc1 < Wn);
            const int ya  = max(y, 0);
            const int xa0 = min(max(xc0, 0), Wn - 1);
            const int xa1 = min(max(xc1, 0), Wn - 1);
            const size_t p0b = ((size_t)(ya * Wn + xa0)) * 256 + 2 * chq;
            const size_t p1b = ((size_t)(ya * Wn + xa1)) * 256 + 2 * chq;

            uint h0[8], l0[8], h1[8], l1[8];
            #pragma unroll
            for (int s = 0; s < 8; ++s) {
                h0[s] = l0[s] = h1[s] = l1[s] = 0u;
                if (ok0) {
                    h0[s] = *reinterpret_cast<const uint*>(xhb + p0b + s * 32);
                    l0[s] = *reinterpret_cast<const uint*>(xlb + p0b + s * 32);
                }
                if (ok1) {
                    h1[s] = *reinterpret_cast<const uint*>(xhb + p1b + s * 32);
                    l1[s] = *reinterpret_cast<const uint*>(xlb + p1b + s * 32);
                }
            }
            uint4 aH[8], aL[8];
            #pragma unroll
            for (int s = 0; s < 8; ++s) {
                const size_t kb = (size_t)((tap * 8 + s) * 4 + g) * 32 + mt * 16 + l15;
                aH[s] = owhV[kb];
                aL[s] = owlV[kb];
            }

            __syncthreads();

            #pragma unroll
            for (int s = 0; s < 8; ++s) {
                colsH[s][ws0] = h0[s];
                colsL[s][ws0] = l0[s];
                colsH[s][ws1] = h1[s];
                colsL[s][ws1] = l1[s];
            }
            __syncthreads();

            #pragma unroll
            for (int s = 0; s < 8; ++s) {
                FragU aHH, aLL, bH, bL;
                aHH.u = aH[s]; aLL.u = aL[s];
                bH.u = reinterpret_cast<const uint4*>(colsH[s])[ridx];
                bL.u = reinterpret_cast<const uint4*>(colsL[s])[ridx];
                acc = __builtin_amdgcn_mfma_f32_16x16x32_bf16(aHH.h, bH.h, acc, 0, 0, 0);
                acc = __builtin_amdgcn_mfma_f32_16x16x32_bf16(aHH.h, bL.h, acc, 0, 0, 0);
                acc = __builtin_amdgcn_mfma_f32_16x16x32_bf16(aLL.h, bH.h, acc, 0, 0, 0);
            }
        }

        // epilogue -> LDS handoff (was: global offm write)
        const int pos = nt4 * 16 + l15;
        #pragma unroll
        for (int j = 0; j < 4; ++j) {
            const int ch = mt * 16 + g * 4 + j;
            if (ch < NCH) {
                float v = acc[j];
                if (ch < 18) v += offb[ch];
                else         v = 2.f / (1.f + expf(-(v + modb[ch - 18])));
                offm_s[ch][pos] = v;
            }
        }
    }
    __syncthreads();   // all cols reads done + offm_s visible

    // ======================= Phase A2: tap tables (r18, reads LDS) =======
    for (int ti = t; ti < 576; ti += 512) {
        const int k = ti >> 6, pos = ti & 63;
        const float dy = offm_s[2 * k][pos];
        const float dx = offm_s[2 * k + 1][pos];
        const float m  = offm_s[18 + k][pos];
        const int ky = k / 3, kx = k % 3;
        const float py = dy + (float)(ky + row - 1);
        const float px = dx + (float)(kx + pos - 1);
        const float y0f = floorf(py), x0f = floorf(px);
        const float fy = py - y0f, fx = px - x0f;
        const int y0 = (int)y0f, x0i = (int)x0f;
        const int y1 = y0 + 1, x1 = x0i + 1;
        const bool vy0 = (y0 >= 0) && (y0 < Hn);
        const bool vy1 = (y1 >= 0) && (y1 < Hn);
        const bool vx0 = (x0i >= 0) && (x0i < Wn);
        const bool vx1 = (x1 >= 0) && (x1 < Wn);
        const int y0c = min(max(y0, 0), Hn - 1);
        const int y1c = min(max(y1, 0), Hn - 1);
        const int x0c = min(max(x0i, 0), Wn - 1);
        const int x1c = min(max(x1, 0), Wn - 1);
        s_off[ti] = make_int4(y0c * Wn + x0c, y0c * Wn + x1c,
                              y1c * Wn + x0c, y1c * Wn + x1c);
        s_wgt[ti] = make_float4(
            (vy0 && vx0) ? (1.f - fy) * (1.f - fx) * m : 0.f,
            (vy0 && vx1) ? (1.f - fy) * fx * m : 0.f,
            (vy1 && vx0) ? fy * (1.f - fx) * m : 0.f,
            (vy1 && vx1) ? fy * fx * m : 0.f);
    }
    __syncthreads();   // tap tables visible before ANY gather

    // ======================= Phase B: deform conv (r18 verbatim) =========
    const ushort* xb = xbf + (size_t)b * PB * 256;
    const int posT = t >> 4;
    const uint4* wvp = reinterpret_cast<const uint4*>(wTb);
    const int o0 = wv * 32;

    int ri[4];
    #pragma unroll
    for (int nt = 0; nt < 4; ++nt) {
        const int p = nt * 16 + l15;
        ri[nt] = p * 4 + (g ^ (p & 3) ^ ((p >> 2) & 3));
    }

    f32x4 acc[2][4];
    #pragma unroll
    for (int ot = 0; ot < 2; ++ot)
        #pragma unroll
        for (int nt = 0; nt < 4; ++nt)
            acc[ot][nt] = (f32x4){0.f, 0.f, 0.f, 0.f};

    #pragma unroll 1
    for (int cch = 0; cch < 18; ++cch) {
        const int tap = cch >> 1, cc0 = (cch & 1) * 128;
        const int4   offA = s_off[tap * 64 + posT];
        const float4 wgtA = s_wgt[tap * 64 + posT];
        const int4   offB = s_off[tap * 64 + posT + 32];
        const float4 wgtB = s_wgt[tap * 64 + posT + 32];
        const ushort* xc = xb + cc0 + 2 * chq;

        // ---- issue 32 bf16 gathers (2 pos x 4 corners x 4 steps) + 8 A-loads
        uint qa[4], qb[4], qc[4], qd[4], ra[4], rb[4], rc[4], rd[4];
        #pragma unroll
        for (int s = 0; s < 4; ++s) {
            const int so = s * 32;
            qa[s] = *reinterpret_cast<const uint*>(xc + (size_t)offA.x * 256 + so);
            qb[s] = *reinterpret_cast<const uint*>(xc + (size_t)offA.y * 256 + so);
            qc[s] = *reinterpret_cast<const uint*>(xc + (size_t)offA.z * 256 + so);
            qd[s] = *reinterpret_cast<const uint*>(xc + (size_t)offA.w * 256 + so);
            ra[s] = *reinterpret_cast<const uint*>(xc + (size_t)offB.x * 256 + so);
            rb[s] = *reinterpret_cast<const uint*>(xc + (size_t)offB.y * 256 + so);
            rc[s] = *reinterpret_cast<const uint*>(xc + (size_t)offB.z * 256 + so);
            rd[s] = *reinterpret_cast<const uint*>(xc + (size_t)offB.w * 256 + so);
        }
        uint4 apre[4][2];
        #pragma unroll
        for (int s = 0; s < 4; ++s) {
            const int kb = (cch * 4 + s) * 4 + g;
            apre[s][0] = wvp[(size_t)kb * 256 + o0 + l15];
            apre[s][1] = wvp[(size_t)kb * 256 + o0 + 16 + l15];
        }

        __syncthreads();   // prior chunk's MFMA reads complete before overwrite

        #pragma unroll
        for (int s = 0; s < 4; ++s) {
            const float v0 = wgtA.x * bflo(qa[s]) + wgtA.y * bflo(qb[s])
                           + wgtA.z * bflo(qc[s]) + wgtA.w * bflo(qd[s]);
            const float v1 = wgtA.x * bfhi(qa[s]) + wgtA.y * bfhi(qb[s])
                           + wgtA.z * bfhi(qc[s]) + wgtA.w * bfhi(qd[s]);
            cols[s][ws0] = (uint)f2bf(v0) | ((uint)f2bf(v1) << 16);
            const float u0 = wgtB.x * bflo(ra[s]) + wgtB.y * bflo(rb[s])
                           + wgtB.z * bflo(rc[s]) + wgtB.w * bflo(rd[s]);
            const float u1 = wgtB.x * bfhi(ra[s]) + wgtB.y * bfhi(rb[s])
                           + wgtB.z * bfhi(rc[s]) + wgtB.w * bfhi(rd[s]);
            cols[s][ws0 + 512] = (uint)f2bf(u0) | ((uint)f2bf(u1) << 16);
        }
        __syncthreads();   // writes visible before MFMA reads

        #pragma unroll
        for (int s = 0; s < 4; ++s) {
            FragU a0, a1, bf[4];
            a0.u = apre[s][0]; a1.u = apre[s][1];
            #pragma unroll
            for (int nt = 0; nt < 4; ++nt)
                bf[nt].u = reinterpret_cast<const uint4*>(cols[s])[ri[nt]];
            #pragma unroll
            for (int nt = 0; nt < 4; ++nt) {
                acc[0][nt] = __builtin_amdgcn_mfma_f32_16x16x32_bf16(
                    a0.h, bf[nt].h, acc[0][nt], 0, 0, 0);
                acc[1][nt] = __builtin_amdgcn_mfma_f32_16x16x32_bf16(
                    a1.h, bf[nt].h, acc[1][nt], 0, 0, 0);
            }
        }
    }

    float* ob = out + (size_t)b * On * PB;
    #pragma unroll
    for (int ot = 0; ot < 2; ++ot)
        #pragma unroll
        for (int nt = 0; nt < 4; ++nt)
            #pragma unroll
            for (int j = 0; j < 4; ++j)
                ob[((size_t)(o0 + ot * 16 + g * 4 + j)) * PB
                   + p0 + nt * 16 + l15] = acc[ot][nt][j];
}

// ---------------------------------------------------------------- launch
extern "C" void kernel_launch(void* const* d_in, const int* in_sizes, int n_in,
                              void* d_out, int out_size, void* d_ws, size_t ws_size,
                              hipStream_t stream)
{
    const float* x    = (const float*)d_in[0];
    const float* offw = (const float*)d_in[1];
    const float* offb = (const float*)d_in[2];
    const float* modw = (const float*)d_in[3];
    const float* modb = (const float*)d_in[4];
    const float* wgt  = (const float*)d_in[5];
    float* out = (float*)d_out;

    char* ws = (char*)d_ws;
    // offm region (first 1,769,472 B) now unused -- layout kept stable.
    ushort* wTb  = (ushort*)(ws + 1769472);      // 1,179,648 B
    ushort* owh  = (ushort*)(ws + 2949120);      // 147,456 B
    ushort* owl  = (ushort*)(ws + 3096576);      // 147,456 B
    ushort* xbf  = (ushort*)(ws + 3244032);      // 8,388,608 B
    ushort* xlr  = (ushort*)(ws + 11632640);     // 8,388,608 B -> 20.0 MB total

    nhwcpack_kernel<<<dim3(512), dim3(256), 0, stream>>>(
        x, wgt, offw, modw, xbf, xlr, wTb, owh, owl);
    offdeform_kernel<<<dim3(256), dim3(512), 0, stream>>>(
        xbf, xlr, offb, modb, owh, owl, wTb, out);
}